// Round 2
// baseline (210.172 us; speedup 1.0000x reference)
//
#include <hip/hip_runtime.h>
#include <hip/hip_fp16.h>

static __device__ __forceinline__ float relu_f(float v) { return v > 0.f ? v : 0.f; }

typedef _Float16 half8 __attribute__((ext_vector_type(8)));
typedef float floatx4 __attribute__((ext_vector_type(4)));

#define ELL 96  // fixed slots per node; in-degree is Poisson(16), P(>96) ~ 1e-40

// ELL entry: low 16 bits = src node (N < 65536), high 16 bits = fp16 weight.
static __device__ __forceinline__ float entry_w(unsigned int pk) {
  return __half2float(__ushort_as_half((unsigned short)(pk >> 16)));
}

// ---------------- K1: count+fill, 4 edges/thread + folded W^T cast ------------
// cnt[i] packed u64: high32 = slot counter, low32 = Sigma(ew) in 8.24 fixed point.
// 4 edges per thread -> 4 independent atomic chains in flight (the atomic RETURN
// is on the critical path: slot store depends on it). Loads vectorized 16 B.

__global__ __launch_bounds__(256) void count_fill_kernel(
    const int* __restrict__ src, const int* __restrict__ dst,
    const float* __restrict__ ew, unsigned long long* __restrict__ cnt,
    unsigned int* __restrict__ epack, int E,
    const float* __restrict__ W, _Float16* __restrict__ wt) {
  int i = blockIdx.x * blockDim.x + threadIdx.x;
  if (i < 128 * 128) {  // fold the fp16 W^T cast into the first 64 blocks (free)
    int k = i >> 7, nn = i & 127;
    wt[nn * 128 + k] = (_Float16)W[i];
  }
  int e0 = i * 4;
  if (e0 >= E) return;
  if (e0 + 3 < E) {
    int4   s4 = *(const int4*)(src + e0);
    int4   d4 = *(const int4*)(dst + e0);
    float4 w4 = *(const float4*)(ew + e0);
    int   ss[4] = {s4.x, s4.y, s4.z, s4.w};
    int   dd[4] = {d4.x, d4.y, d4.z, d4.w};
    float ww[4] = {w4.x, w4.y, w4.z, w4.w};
    #pragma unroll
    for (int u = 0; u < 4; ++u) {
      unsigned long long pk = (1ull << 32) |
          (unsigned long long)__float2uint_rn(ww[u] * 16777216.f);
      unsigned long long old = atomicAdd(&cnt[dd[u]], pk);
      unsigned int r = (unsigned int)(old >> 32);
      if (r < ELL) {
        unsigned short w16 = __half_as_ushort(__float2half_rn(ww[u]));
        epack[(size_t)dd[u] * ELL + r] = (unsigned int)ss[u] | ((unsigned int)w16 << 16);
      }
    }
  } else {
    for (int e = e0; e < E; ++e) {
      float w = ew[e];
      unsigned long long pk = (1ull << 32) |
          (unsigned long long)__float2uint_rn(w * 16777216.f);
      unsigned long long old = atomicAdd(&cnt[dst[e]], pk);
      unsigned int r = (unsigned int)(old >> 32);
      if (r < ELL) {
        unsigned short w16 = __half_as_ushort(__float2half_rn(w));
        epack[(size_t)dst[e] * ELL + r] = (unsigned int)src[e] | ((unsigned int)w16 << 16);
      }
    }
  }
}

// ---------------- K2: coalesced premul cast: xh[i] = fp16(x[i] * dinv[i]) -----

__global__ void premul_cast_kernel(const float4* __restrict__ x4,
                                   const unsigned long long* __restrict__ cnt,
                                   half8* __restrict__ xh8, int n) {
  int j = blockIdx.x * blockDim.x + threadIdx.x;
  if (j >= n * 16) return;
  int node = j >> 4;  // 16 threads per node share one cnt load (L1 broadcast)
  unsigned long long cv = cnt[node];
  float deg = 1.f + (float)(unsigned int)cv * (1.f / 16777216.f);  // +1 = self-loop
  float dinv = rsqrtf(deg);
  float4 a = x4[2 * j], b = x4[2 * j + 1];
  half8 o;
  o[0] = (_Float16)(a.x * dinv); o[1] = (_Float16)(a.y * dinv);
  o[2] = (_Float16)(a.z * dinv); o[3] = (_Float16)(a.w * dinv);
  o[4] = (_Float16)(b.x * dinv); o[5] = (_Float16)(b.y * dinv);
  o[6] = (_Float16)(b.z * dinv); o[7] = (_Float16)(b.w * dinv);
  xh8[j] = o;
}

// ---------------- K3: fused aggregate + MFMA GEMM + pooling --------------------
// Block = 256 threads = 4 waves, owns 64 nodes. epack pair for batch j+8 is
// prefetched while batch j's gathers/FMAs run, so steady state exposes only the
// hx gather latency.

__global__ __launch_bounds__(256) void agg_gemm_pool_kernel(const half8* __restrict__ xh8,
    const unsigned long long* __restrict__ cnt,
    const unsigned int* __restrict__ epack, const _Float16* __restrict__ wt,
    const float* __restrict__ bias, const int* __restrict__ batch,
    float* __restrict__ gmax, float* __restrict__ gsum, float* __restrict__ gcnt, int n) {
  __shared__ float sH[64 * 129];                 // 33 KB; first used as fp16 sAgg
  _Float16* sAgg = (_Float16*)sH;                // stride 136 halves (272 B)
  __shared__ int sBatch[64];
  int tid = threadIdx.x;
  int w = tid >> 6, lane = tid & 63;
  int grp = lane >> 4, sub = lane & 15;
  int quad = lane >> 4, c15 = lane & 15;
  int row0 = blockIdx.x * 64;
  int nb = n - row0; if (nb > 64) nb = 64;

  // ---- Phase 1: aggregate 16 nodes per wave into sAgg ----
  #pragma unroll
  for (int it = 0; it < 4; ++it) {
    int rloc = w * 16 + it * 4 + grp;
    int node = row0 + rloc;
    if (node >= n) node = n - 1;  // clamped rows produce garbage discarded by nb guard
    unsigned long long cv = cnt[node];
    int deg = (int)(unsigned int)(cv >> 32);
    if (deg > ELL) deg = ELL;
    float dn = rsqrtf(1.f + (float)(unsigned int)cv * (1.f / 16777216.f));
    half8 xv = xh8[(size_t)node * 16 + sub];     // already x*dinv[node]
    float acc[8];
    #pragma unroll
    for (int c = 0; c < 8; ++c) acc[c] = dn * (float)xv[c];  // self: dinv^2 * x
    size_t base = (size_t)node * ELL;
    int dlen = (deg + 7) & ~7;
    uint4 pa, pb;
    if (dlen > 0) {
      pa = *(const uint4*)&epack[base];
      pb = *(const uint4*)&epack[base + 4];
    }
    for (int j = 0; j < dlen; j += 8) {
      // prefetch next batch's packed entries (clamped addr stays in-row, L1-hot)
      size_t nxt = (j + 8 < dlen) ? base + j + 8 : base;
      uint4 na = *(const uint4*)&epack[nxt];
      uint4 nb2 = *(const uint4*)&epack[nxt + 4];
      unsigned int pk[8] = {pa.x, pa.y, pa.z, pa.w, pb.x, pb.y, pb.z, pb.w};
      half8 hx[8];
      #pragma unroll
      for (int u = 0; u < 8; ++u) {
        // tail slots are unwritten garbage: redirect to own row (always valid fp16)
        int sidx = (j + u < deg) ? (int)(pk[u] & 0xFFFFu) : node;
        hx[u] = xh8[(size_t)sidx * 16 + sub];    // already x*dinv[src]
      }
      #pragma unroll
      for (int u = 0; u < 8; ++u) {
        float wgt = (j + u < deg) ? entry_w(pk[u]) * dn : 0.f;
        #pragma unroll
        for (int c = 0; c < 8; ++c) acc[c] += wgt * (float)hx[u][c];
      }
      pa = na; pb = nb2;
    }
    half8 outv;
    #pragma unroll
    for (int c = 0; c < 8; ++c) outv[c] = (_Float16)acc[c];
    *(half8*)&sAgg[rloc * 136 + sub * 8] = outv;
  }
  __syncthreads();

  // ---- Phase 2: MFMA from LDS A-fragments ----
  half8 af[4];
  #pragma unroll
  for (int ks = 0; ks < 4; ++ks)
    af[ks] = *(const half8*)&sAgg[(w * 16 + c15) * 136 + ks * 32 + quad * 8];
  if (tid < nb) sBatch[tid] = batch[row0 + tid];
  __syncthreads();  // all sAgg reads done before sH overwrite

  float bb[8];
  #pragma unroll
  for (int j = 0; j < 8; ++j) bb[j] = bias[j * 16 + c15];

  floatx4 acc[8] = {};
  #pragma unroll
  for (int ks = 0; ks < 4; ++ks) {
    #pragma unroll
    for (int j = 0; j < 8; ++j) {
      const half8* bptr =
          (const half8*)(wt + (size_t)(j * 16 + c15) * 128 + ks * 32 + quad * 8);
      acc[j] = __builtin_amdgcn_mfma_f32_16x16x32_f16(af[ks], *bptr, acc[j], 0, 0, 0);
    }
  }

  #pragma unroll
  for (int j = 0; j < 8; ++j) {
    int col = j * 16 + c15;
    #pragma unroll
    for (int r = 0; r < 4; ++r) {
      int row = w * 16 + quad * 4 + r;
      if (row < nb) sH[row * 129 + col] = relu_f(acc[j][r] + bb[j]);
    }
  }
  __syncthreads();

  // ---- Phase 3: segment pooling ----
  if (tid < 128) {
    int c = tid;
    int cur = sBatch[0];
    float mx = 0.f, sm = 0.f;
    int cnt_ = 0;
    for (int r = 0; r < nb; ++r) {
      int g = sBatch[r];
      if (g != cur) {
        atomicMax((int*)&gmax[cur * 128 + c], __float_as_int(mx));
        atomicAdd(&gsum[cur * 128 + c], sm);
        if (c == 0) atomicAdd(&gcnt[cur], (float)cnt_);
        mx = 0.f; sm = 0.f; cnt_ = 0; cur = g;
      }
      float v = sH[r * 129 + c];
      mx = fmaxf(mx, v);
      sm += v;
      ++cnt_;
    }
    atomicMax((int*)&gmax[cur * 128 + c], __float_as_int(mx));
    atomicAdd(&gsum[cur * 128 + c], sm);
    if (c == 0) atomicAdd(&gcnt[cur], (float)cnt_);
  }
}

// ---------------- K4: MLP, one block per graph, split-k over 256 threads ------

__global__ __launch_bounds__(256) void mlp_kernel(const float* __restrict__ gmax,
    const float* __restrict__ gsum, const float* __restrict__ gcnt,
    const float* __restrict__ rho,
    const float* __restrict__ w1, const float* __restrict__ b1,
    const float* __restrict__ w2, const float* __restrict__ b2,
    const float* __restrict__ w3, const float* __restrict__ b3,
    float* __restrict__ out) {
  __shared__ float s_in[257];
  __shared__ float s_part[256];
  __shared__ float s_z1[128];
  __shared__ float s_z2[128];
  int g = blockIdx.x, t = threadIdx.x;
  int col = t & 127, seg = t >> 7;  // seg uniform per wave (waves 0-1 vs 2-3)
  float inv_cnt = 1.f / fmaxf(gcnt[g], 1.f);
  if (t < 128) s_in[t] = gmax[g * 128 + t];
  else         s_in[t] = gsum[g * 128 + (t - 128)] * inv_cnt;
  if (t == 0)  s_in[256] = rho[g];
  __syncthreads();

  float s = seg ? 0.f : b1[col];
  {
    int k0 = seg ? 128 : 0, k1 = seg ? 257 : 128;
    for (int k = k0; k < k1; ++k) s += s_in[k] * w1[k * 128 + col];
  }
  s_part[t] = s;
  __syncthreads();
  if (t < 128) s_z1[t] = relu_f(s_part[t] + s_part[t + 128]);
  __syncthreads();

  s = seg ? 0.f : b2[col];
  {
    int k0 = seg * 64;
    for (int k = k0; k < k0 + 64; ++k) s += s_z1[k] * w2[k * 128 + col];
  }
  s_part[t] = s;
  __syncthreads();
  if (t < 128) s_z2[t] = relu_f(s_part[t] + s_part[t + 128]);
  __syncthreads();

  if (t < 72) {
    int oc = t % 36, sg = t / 36;
    s = sg ? 0.f : b3[oc];
    int k0 = sg * 64;
    for (int k = k0; k < k0 + 64; ++k) s += s_z2[k] * w3[k * 36 + oc];
    s_part[t] = s;
  }
  __syncthreads();
  if (t < 36) out[g * 36 + t] = s_part[t] + s_part[t + 36];
}

// ---------------- launch ----------------

extern "C" void kernel_launch(void* const* d_in, const int* in_sizes, int n_in,
                              void* d_out, int out_size, void* d_ws, size_t ws_size,
                              hipStream_t stream) {
  const float* x      = (const float*)d_in[0];
  const float* ew     = (const float*)d_in[1];
  const float* rho    = (const float*)d_in[2];
  const float* conv_w = (const float*)d_in[3];
  const float* conv_b = (const float*)d_in[4];
  const float* w1 = (const float*)d_in[5];
  const float* b1 = (const float*)d_in[6];
  const float* w2 = (const float*)d_in[7];
  const float* b2 = (const float*)d_in[8];
  const float* w3 = (const float*)d_in[9];
  const float* b3 = (const float*)d_in[10];
  const int* eidx  = (const int*)d_in[11];
  const int* batch = (const int*)d_in[12];

  const int N = in_sizes[0] / 128;
  const int E = in_sizes[1];
  const int G = in_sizes[2];
  const int* srcp = eidx;
  const int* dstp = eidx + E;

  char* p = (char*)d_ws;
  auto carve = [&](size_t bytes) { char* r = p; p += (bytes + 255) & ~(size_t)255; return (void*)r; };
  // Contiguous zero block: one hipMemsetAsync replaces the init kernel.
  char* zbase = p;
  unsigned long long* cnt  = (unsigned long long*)carve((size_t)N * 8);
  float*              gmax = (float*)             carve((size_t)G * 128 * 4);
  float*              gsum = (float*)             carve((size_t)G * 128 * 4);
  float*              gcnt = (float*)             carve((size_t)G * 4);
  size_t zbytes = (size_t)(p - zbase);
  unsigned int* epack = (unsigned int*)carve((size_t)N * ELL * 4);
  half8*        xh    = (half8*)       carve((size_t)N * 128 * 2);
  _Float16*     wt    = (_Float16*)    carve((size_t)128 * 128 * 2);

  hipMemsetAsync(zbase, 0, zbytes, stream);

  int nthr_cf = (E + 3) / 4;
  if (nthr_cf < 128 * 128) nthr_cf = 128 * 128;  // cover the folded W^T cast
  count_fill_kernel<<<(nthr_cf + 255) / 256, 256, 0, stream>>>(srcp, dstp, ew, cnt,
                                                               epack, E, conv_w, wt);
  premul_cast_kernel<<<(N * 16 + 255) / 256, 256, 0, stream>>>((const float4*)x, cnt, xh, N);
  agg_gemm_pool_kernel<<<(N + 63) / 64, 256, 0, stream>>>(xh, cnt, epack, wt, conv_b,
                                                          batch, gmax, gsum, gcnt, N);
  mlp_kernel<<<G, 256, 0, stream>>>(gmax, gsum, gcnt, rho, w1, b1, w2, b2, w3, b3,
                                    (float*)d_out);
}

// Round 3
// 173.191 us; speedup vs baseline: 1.2135x; 1.2135x over previous
//
#include <hip/hip_runtime.h>
#include <hip/hip_fp16.h>

static __device__ __forceinline__ float relu_f(float v) { return v > 0.f ? v : 0.f; }

typedef _Float16 half8 __attribute__((ext_vector_type(8)));
typedef float floatx4 __attribute__((ext_vector_type(4)));

#define ELL 96  // fixed slots per node; in-degree is Poisson(16), P(>96) ~ 1e-40

// ELL entry: low 16 bits = src node (N < 65536), high 16 bits = fp16 weight.
static __device__ __forceinline__ float entry_w(unsigned int pk) {
  return __half2float(__ushort_as_half((unsigned short)(pk >> 16)));
}

// ---------------- K1: count+fill + folded weight transposes -------------------
// cnt[i] packed u64: high32 = slot counter, low32 = Sigma(ew) in 8.24 fixed point.
// 4 edges per thread -> 4 independent atomic chains in flight. Spare low-index
// threads also emit the fp16 W^T (conv) and fp32 transposed MLP weights so the
// MLP kernel can do contiguous float4 weight loads (w1t row stride 260 floats =
// 1040 B, 16 B aligned).

__global__ __launch_bounds__(256) void count_fill_kernel(
    const int* __restrict__ src, const int* __restrict__ dst,
    const float* __restrict__ ew, unsigned long long* __restrict__ cnt,
    unsigned int* __restrict__ epack, int E,
    const float* __restrict__ W, _Float16* __restrict__ wt,
    const float* __restrict__ w1, float* __restrict__ w1t,
    const float* __restrict__ w2, float* __restrict__ w2t,
    const float* __restrict__ w3, float* __restrict__ w3t) {
  int i = blockIdx.x * blockDim.x + threadIdx.x;
  if (i < 16384) {                       // conv W -> fp16 W^T [128][128]
    int k = i >> 7, c = i & 127;
    wt[c * 128 + k] = (_Float16)W[i];
  } else if (i < 16384 + 32896) {        // w1 [257][128] -> w1t [128][260]
    int j = i - 16384;
    int k = j >> 7, c = j & 127;
    w1t[c * 260 + k] = w1[j];
  } else if (i < 16384 + 32896 + 16384) {  // w2 [128][128] -> w2t [128][128]
    int j = i - (16384 + 32896);
    int k = j >> 7, c = j & 127;
    w2t[c * 128 + k] = w2[j];
  } else if (i < 16384 + 32896 + 16384 + 4608) {  // w3 [128][36] -> w3t [36][128]
    int j = i - (16384 + 32896 + 16384);
    int k = j / 36, c = j - k * 36;
    w3t[c * 128 + k] = w3[j];
  }
  int e0 = i * 4;
  if (e0 >= E) return;
  if (e0 + 3 < E) {
    int4   s4 = *(const int4*)(src + e0);
    int4   d4 = *(const int4*)(dst + e0);
    float4 w4 = *(const float4*)(ew + e0);
    int   ss[4] = {s4.x, s4.y, s4.z, s4.w};
    int   dd[4] = {d4.x, d4.y, d4.z, d4.w};
    float ww[4] = {w4.x, w4.y, w4.z, w4.w};
    #pragma unroll
    for (int u = 0; u < 4; ++u) {
      unsigned long long pk = (1ull << 32) |
          (unsigned long long)__float2uint_rn(ww[u] * 16777216.f);
      unsigned long long old = atomicAdd(&cnt[dd[u]], pk);
      unsigned int r = (unsigned int)(old >> 32);
      if (r < ELL) {
        unsigned short w16 = __half_as_ushort(__float2half_rn(ww[u]));
        epack[(size_t)dd[u] * ELL + r] = (unsigned int)ss[u] | ((unsigned int)w16 << 16);
      }
    }
  } else {
    for (int e = e0; e < E; ++e) {
      float w = ew[e];
      unsigned long long pk = (1ull << 32) |
          (unsigned long long)__float2uint_rn(w * 16777216.f);
      unsigned long long old = atomicAdd(&cnt[dst[e]], pk);
      unsigned int r = (unsigned int)(old >> 32);
      if (r < ELL) {
        unsigned short w16 = __half_as_ushort(__float2half_rn(w));
        epack[(size_t)dst[e] * ELL + r] = (unsigned int)src[e] | ((unsigned int)w16 << 16);
      }
    }
  }
}

// ---------------- K2: coalesced premul cast: xh[i] = fp16(x[i] * dinv[i]) -----

__global__ void premul_cast_kernel(const float4* __restrict__ x4,
                                   const unsigned long long* __restrict__ cnt,
                                   half8* __restrict__ xh8, int n) {
  int j = blockIdx.x * blockDim.x + threadIdx.x;
  if (j >= n * 16) return;
  int node = j >> 4;  // 16 threads per node share one cnt load (L1 broadcast)
  unsigned long long cv = cnt[node];
  float deg = 1.f + (float)(unsigned int)cv * (1.f / 16777216.f);  // +1 = self-loop
  float dinv = rsqrtf(deg);
  float4 a = x4[2 * j], b = x4[2 * j + 1];
  half8 o;
  o[0] = (_Float16)(a.x * dinv); o[1] = (_Float16)(a.y * dinv);
  o[2] = (_Float16)(a.z * dinv); o[3] = (_Float16)(a.w * dinv);
  o[4] = (_Float16)(b.x * dinv); o[5] = (_Float16)(b.y * dinv);
  o[6] = (_Float16)(b.z * dinv); o[7] = (_Float16)(b.w * dinv);
  xh8[j] = o;
}

// ---------------- K3: fused aggregate + MFMA GEMM + pooling --------------------
// Block = 256 threads = 4 waves, owns 64 nodes. epack pair for batch j+8 is
// prefetched while batch j's gathers/FMAs run.

__global__ __launch_bounds__(256) void agg_gemm_pool_kernel(const half8* __restrict__ xh8,
    const unsigned long long* __restrict__ cnt,
    const unsigned int* __restrict__ epack, const _Float16* __restrict__ wt,
    const float* __restrict__ bias, const int* __restrict__ batch,
    float* __restrict__ gmax, float* __restrict__ gsum, float* __restrict__ gcnt, int n) {
  __shared__ float sH[64 * 129];                 // 33 KB; first used as fp16 sAgg
  _Float16* sAgg = (_Float16*)sH;                // stride 136 halves (272 B)
  __shared__ int sBatch[64];
  int tid = threadIdx.x;
  int w = tid >> 6, lane = tid & 63;
  int grp = lane >> 4, sub = lane & 15;
  int quad = lane >> 4, c15 = lane & 15;
  int row0 = blockIdx.x * 64;
  int nb = n - row0; if (nb > 64) nb = 64;

  // ---- Phase 1: aggregate 16 nodes per wave into sAgg ----
  #pragma unroll
  for (int it = 0; it < 4; ++it) {
    int rloc = w * 16 + it * 4 + grp;
    int node = row0 + rloc;
    if (node >= n) node = n - 1;  // clamped rows produce garbage discarded by nb guard
    unsigned long long cv = cnt[node];
    int deg = (int)(unsigned int)(cv >> 32);
    if (deg > ELL) deg = ELL;
    float dn = rsqrtf(1.f + (float)(unsigned int)cv * (1.f / 16777216.f));
    half8 xv = xh8[(size_t)node * 16 + sub];     // already x*dinv[node]
    float acc[8];
    #pragma unroll
    for (int c = 0; c < 8; ++c) acc[c] = dn * (float)xv[c];  // self: dinv^2 * x
    size_t base = (size_t)node * ELL;
    int dlen = (deg + 7) & ~7;
    uint4 pa, pb;
    if (dlen > 0) {
      pa = *(const uint4*)&epack[base];
      pb = *(const uint4*)&epack[base + 4];
    }
    for (int j = 0; j < dlen; j += 8) {
      size_t nxt = (j + 8 < dlen) ? base + j + 8 : base;
      uint4 na = *(const uint4*)&epack[nxt];
      uint4 nb2 = *(const uint4*)&epack[nxt + 4];
      unsigned int pk[8] = {pa.x, pa.y, pa.z, pa.w, pb.x, pb.y, pb.z, pb.w};
      half8 hx[8];
      #pragma unroll
      for (int u = 0; u < 8; ++u) {
        int sidx = (j + u < deg) ? (int)(pk[u] & 0xFFFFu) : node;
        hx[u] = xh8[(size_t)sidx * 16 + sub];    // already x*dinv[src]
      }
      #pragma unroll
      for (int u = 0; u < 8; ++u) {
        float wgt = (j + u < deg) ? entry_w(pk[u]) * dn : 0.f;
        #pragma unroll
        for (int c = 0; c < 8; ++c) acc[c] += wgt * (float)hx[u][c];
      }
      pa = na; pb = nb2;
    }
    half8 outv;
    #pragma unroll
    for (int c = 0; c < 8; ++c) outv[c] = (_Float16)acc[c];
    *(half8*)&sAgg[rloc * 136 + sub * 8] = outv;
  }
  __syncthreads();

  // ---- Phase 2: MFMA from LDS A-fragments ----
  half8 af[4];
  #pragma unroll
  for (int ks = 0; ks < 4; ++ks)
    af[ks] = *(const half8*)&sAgg[(w * 16 + c15) * 136 + ks * 32 + quad * 8];
  if (tid < nb) sBatch[tid] = batch[row0 + tid];
  __syncthreads();  // all sAgg reads done before sH overwrite

  float bb[8];
  #pragma unroll
  for (int j = 0; j < 8; ++j) bb[j] = bias[j * 16 + c15];

  floatx4 acc[8] = {};
  #pragma unroll
  for (int ks = 0; ks < 4; ++ks) {
    #pragma unroll
    for (int j = 0; j < 8; ++j) {
      const half8* bptr =
          (const half8*)(wt + (size_t)(j * 16 + c15) * 128 + ks * 32 + quad * 8);
      acc[j] = __builtin_amdgcn_mfma_f32_16x16x32_f16(af[ks], *bptr, acc[j], 0, 0, 0);
    }
  }

  #pragma unroll
  for (int j = 0; j < 8; ++j) {
    int col = j * 16 + c15;
    #pragma unroll
    for (int r = 0; r < 4; ++r) {
      int row = w * 16 + quad * 4 + r;
      if (row < nb) sH[row * 129 + col] = relu_f(acc[j][r] + bb[j]);
    }
  }
  __syncthreads();

  // ---- Phase 3: segment pooling ----
  if (tid < 128) {
    int c = tid;
    int cur = sBatch[0];
    float mx = 0.f, sm = 0.f;
    int cnt_ = 0;
    for (int r = 0; r < nb; ++r) {
      int g = sBatch[r];
      if (g != cur) {
        atomicMax((int*)&gmax[cur * 128 + c], __float_as_int(mx));
        atomicAdd(&gsum[cur * 128 + c], sm);
        if (c == 0) atomicAdd(&gcnt[cur], (float)cnt_);
        mx = 0.f; sm = 0.f; cnt_ = 0; cur = g;
      }
      float v = sH[r * 129 + c];
      mx = fmaxf(mx, v);
      sm += v;
      ++cnt_;
    }
    atomicMax((int*)&gmax[cur * 128 + c], __float_as_int(mx));
    atomicAdd(&gsum[cur * 128 + c], sm);
    if (c == 0) atomicAdd(&gcnt[cur], (float)cnt_);
  }
}

// ---------------- K4: MLP with transposed weights -----------------------------
// One block/graph, 256 threads = 2-way split-k over 128 cols. ALL inner loops
// have compile-time trip counts (full unroll -> deep load pipeline; round-2's
// runtime bounds killed unrolling and cost 55 us). Weight rows are contiguous
// float4-aligned (w1t stride 260), so each thread issues unrolled dwordx4 loads.

__global__ __launch_bounds__(256) void mlp_kernel(const float* __restrict__ gmax,
    const float* __restrict__ gsum, const float* __restrict__ gcnt,
    const float* __restrict__ rho,
    const float* __restrict__ w1t, const float* __restrict__ b1,
    const float* __restrict__ w2t, const float* __restrict__ b2,
    const float* __restrict__ w3t, const float* __restrict__ b3,
    float* __restrict__ out) {
  __shared__ float s_in[260];
  __shared__ float s_part[256];
  __shared__ float s_z1[128];
  __shared__ float s_z2[128];
  int g = blockIdx.x, t = threadIdx.x;
  int col = t & 127, seg = t >> 7;  // seg uniform per wave (waves 0-1 vs 2-3)
  float inv_cnt = 1.f / fmaxf(gcnt[g], 1.f);
  if (t < 128) s_in[t] = gmax[g * 128 + t];
  else         s_in[t] = gsum[g * 128 + col] * inv_cnt;
  if (t == 0)  s_in[256] = rho[g];
  __syncthreads();

  // ---- layer 1: 257-dot split 128|129 ----
  float s;
  {
    const float4* wp = (const float4*)(w1t + (size_t)col * 260 + seg * 128);
    const float4* sp = (const float4*)(s_in + seg * 128);
    float a = 0.f, b = 0.f;
    #pragma unroll
    for (int q = 0; q < 32; q += 2) {
      float4 u0 = wp[q],     i0 = sp[q];
      float4 u1 = wp[q + 1], i1 = sp[q + 1];
      a += u0.x * i0.x + u0.y * i0.y + u0.z * i0.z + u0.w * i0.w;
      b += u1.x * i1.x + u1.y * i1.y + u1.z * i1.z + u1.w * i1.w;
    }
    s = a + b;
    s += seg ? s_in[256] * w1t[(size_t)col * 260 + 256] : b1[col];
  }
  s_part[t] = s;
  __syncthreads();
  if (t < 128) s_z1[t] = relu_f(s_part[t] + s_part[t + 128]);
  __syncthreads();

  // ---- layer 2: 128-dot split 64|64 ----
  {
    const float4* wp = (const float4*)(w2t + (size_t)col * 128 + seg * 64);
    const float4* sp = (const float4*)(s_z1 + seg * 64);
    float a = 0.f, b = 0.f;
    #pragma unroll
    for (int q = 0; q < 16; q += 2) {
      float4 u0 = wp[q],     i0 = sp[q];
      float4 u1 = wp[q + 1], i1 = sp[q + 1];
      a += u0.x * i0.x + u0.y * i0.y + u0.z * i0.z + u0.w * i0.w;
      b += u1.x * i1.x + u1.y * i1.y + u1.z * i1.z + u1.w * i1.w;
    }
    s = a + b + (seg ? 0.f : b2[col]);
  }
  s_part[t] = s;
  __syncthreads();
  if (t < 128) s_z2[t] = relu_f(s_part[t] + s_part[t + 128]);
  __syncthreads();

  // ---- layer 3: 36 cols x 4 k-segments of 32 ----
  if (t < 144) {
    int oc = t % 36, sg = t / 36;
    const float4* wp = (const float4*)(w3t + (size_t)oc * 128 + sg * 32);
    const float4* sp = (const float4*)(s_z2 + sg * 32);
    float a = 0.f;
    #pragma unroll
    for (int q = 0; q < 8; ++q) {
      float4 u = wp[q], iv = sp[q];
      a += u.x * iv.x + u.y * iv.y + u.z * iv.z + u.w * iv.w;
    }
    s_part[t] = a;
  }
  __syncthreads();
  if (t < 36)
    out[g * 36 + t] = b3[t] + s_part[t] + s_part[t + 36] + s_part[t + 72] + s_part[t + 108];
}

// ---------------- launch ----------------

extern "C" void kernel_launch(void* const* d_in, const int* in_sizes, int n_in,
                              void* d_out, int out_size, void* d_ws, size_t ws_size,
                              hipStream_t stream) {
  const float* x      = (const float*)d_in[0];
  const float* ew     = (const float*)d_in[1];
  const float* rho    = (const float*)d_in[2];
  const float* conv_w = (const float*)d_in[3];
  const float* conv_b = (const float*)d_in[4];
  const float* w1 = (const float*)d_in[5];
  const float* b1 = (const float*)d_in[6];
  const float* w2 = (const float*)d_in[7];
  const float* b2 = (const float*)d_in[8];
  const float* w3 = (const float*)d_in[9];
  const float* b3 = (const float*)d_in[10];
  const int* eidx  = (const int*)d_in[11];
  const int* batch = (const int*)d_in[12];

  const int N = in_sizes[0] / 128;
  const int E = in_sizes[1];
  const int G = in_sizes[2];
  const int* srcp = eidx;
  const int* dstp = eidx + E;

  char* p = (char*)d_ws;
  auto carve = [&](size_t bytes) { char* r = p; p += (bytes + 255) & ~(size_t)255; return (void*)r; };
  // Contiguous zero block: one hipMemsetAsync replaces the init kernel.
  char* zbase = p;
  unsigned long long* cnt  = (unsigned long long*)carve((size_t)N * 8);
  float*              gmax = (float*)             carve((size_t)G * 128 * 4);
  float*              gsum = (float*)             carve((size_t)G * 128 * 4);
  float*              gcnt = (float*)             carve((size_t)G * 4);
  size_t zbytes = (size_t)(p - zbase);
  unsigned int* epack = (unsigned int*)carve((size_t)N * ELL * 4);
  half8*        xh    = (half8*)       carve((size_t)N * 128 * 2);
  _Float16*     wt    = (_Float16*)    carve((size_t)128 * 128 * 2);
  float*        w1t   = (float*)       carve((size_t)128 * 260 * 4);
  float*        w2t   = (float*)       carve((size_t)128 * 128 * 4);
  float*        w3t   = (float*)       carve((size_t)36 * 128 * 4);

  hipMemsetAsync(zbase, 0, zbytes, stream);

  int nthr_cf = (E + 3) / 4;
  if (nthr_cf < 70272) nthr_cf = 70272;  // cover folded weight transposes
  count_fill_kernel<<<(nthr_cf + 255) / 256, 256, 0, stream>>>(srcp, dstp, ew, cnt,
                                                               epack, E, conv_w, wt,
                                                               w1, w1t, w2, w2t, w3, w3t);
  premul_cast_kernel<<<(N * 16 + 255) / 256, 256, 0, stream>>>((const float4*)x, cnt, xh, N);
  agg_gemm_pool_kernel<<<(N + 63) / 64, 256, 0, stream>>>(xh, cnt, epack, wt, conv_b,
                                                          batch, gmax, gsum, gcnt, N);
  mlp_kernel<<<G, 256, 0, stream>>>(gmax, gsum, gcnt, rho, w1t, b1, w2t, b2, w3t, b3,
                                    (float*)d_out);
}